// Round 6
// baseline (195.176 us; speedup 1.0000x reference)
//
#include <hip/hip_runtime.h>
#include <math.h>

#define NTHR 256
#define K_FINE 2048
#define HW 147456          // 384*384
#define N1 1179648         // 8*HW
#define IMG 384
#define NHC 24             // hist chunks per batch
#define NHIST 192          // 8*24
#define NTILE 1152         // 8 * 144 ssim tiles
#define TOTAL (NTILE + NHIST)   // 1344 main work items
#define NSOFT 256

// ws word offsets
#define WS_PMM   0                          // [3][256][2] floats
#define WS_CTR   1536                       // counters: fin, histdone, sdone (+pad)
#define WS_CHIST 1544                       // 192 * 2048 ints (per-chunk, overwritten)
#define WS_DEPTH (WS_CHIST + NHIST*K_FINE)  // 192 floats
#define WS_SSIM  (WS_DEPTH + NHIST)         // 1152 floats
#define WS_UNIF  (WS_SSIM + NTILE)          // 256 floats

#define CTR_FIN  0
#define CTR_HIST 1
#define CTR_SOFT 2

#define HRS (42*33)
#define SMEMF (42*43*2 + 3*HRS)             // 7770 floats = 31.1 KB

__device__ __forceinline__ void spin_geq(int* p, int target) {
    while (__hip_atomic_load(p, __ATOMIC_ACQUIRE, __HIP_MEMORY_SCOPE_AGENT) < target)
        __builtin_amdgcn_s_sleep(16);
}

// ================= K1: per-block min/max partials; zero counters ============
__global__ __launch_bounds__(NTHR) void k_minmax(
        const float* __restrict__ x, const float* __restrict__ tg,
        const float* __restrict__ dp, float* __restrict__ wsf)
{
    __shared__ float swred[4][8];
    const int tid = threadIdx.x, bid = blockIdx.x;
    const float4* x4 = (const float4*)x  + bid * 1152;
    const float4* t4 = (const float4*)tg + bid * 1152;
    const float4* d4 = (const float4*)dp + bid * 1152;
    float mn0 = 3.4e38f, mx0 = -3.4e38f;
    float mn1 = 3.4e38f, mx1 = -3.4e38f;
    float mn2 = 3.4e38f, mx2 = -3.4e38f;
    for (int i = tid; i < 1152; i += NTHR) {
        float4 v = x4[i];
        mn0 = fminf(mn0, fminf(fminf(v.x, v.y), fminf(v.z, v.w)));
        mx0 = fmaxf(mx0, fmaxf(fmaxf(v.x, v.y), fmaxf(v.z, v.w)));
        v = t4[i];
        mn1 = fminf(mn1, fminf(fminf(v.x, v.y), fminf(v.z, v.w)));
        mx1 = fmaxf(mx1, fmaxf(fmaxf(v.x, v.y), fmaxf(v.z, v.w)));
        v = d4[i];
        mn2 = fminf(mn2, fminf(fminf(v.x, v.y), fminf(v.z, v.w)));
        mx2 = fmaxf(mx2, fmaxf(fmaxf(v.x, v.y), fmaxf(v.z, v.w)));
    }
    #pragma unroll
    for (int off = 32; off; off >>= 1) {
        mn0 = fminf(mn0, __shfl_down(mn0, off, 64));
        mx0 = fmaxf(mx0, __shfl_down(mx0, off, 64));
        mn1 = fminf(mn1, __shfl_down(mn1, off, 64));
        mx1 = fmaxf(mx1, __shfl_down(mx1, off, 64));
        mn2 = fminf(mn2, __shfl_down(mn2, off, 64));
        mx2 = fmaxf(mx2, __shfl_down(mx2, off, 64));
    }
    if ((tid & 63) == 0) {
        int w = tid >> 6;
        swred[w][0] = mn0; swred[w][1] = mx0; swred[w][2] = mn1;
        swred[w][3] = mx1; swred[w][4] = mn2; swred[w][5] = mx2;
    }
    __syncthreads();
    if (tid == 0) {
        #pragma unroll
        for (int w = 1; w < 4; w++) {
            swred[0][0] = fminf(swred[0][0], swred[w][0]);
            swred[0][1] = fmaxf(swred[0][1], swred[w][1]);
            swred[0][2] = fminf(swred[0][2], swred[w][2]);
            swred[0][3] = fmaxf(swred[0][3], swred[w][3]);
            swred[0][4] = fminf(swred[0][4], swred[w][4]);
            swred[0][5] = fmaxf(swred[0][5], swred[w][5]);
        }
        wsf[WS_PMM +        bid * 2]     = swred[0][0];
        wsf[WS_PMM +        bid * 2 + 1] = swred[0][1];
        wsf[WS_PMM + 512  + bid * 2]     = swred[0][2];
        wsf[WS_PMM + 512  + bid * 2 + 1] = swred[0][3];
        wsf[WS_PMM + 1024 + bid * 2]     = swred[0][4];
        wsf[WS_PMM + 1024 + bid * 2 + 1] = swred[0][5];
    }
    if (bid == 0 && tid < 8) ((int*)wsf)[WS_CTR + tid] = 0;
}

// helper: per-block redundant global min/max reduce from partials
__device__ __forceinline__ void reduce_minmax(
        const float* __restrict__ wsf, float swred[4][8], int tid,
        float& xmn, float& xinv, float& tmn, float& tinv, float& dmn, float& dinv)
{
    const float2* pm = (const float2*)&wsf[WS_PMM];
    float2 a = pm[tid], b = pm[256 + tid], c = pm[512 + tid];
    float mn0 = a.x, mx0 = a.y, mn1 = b.x, mx1 = b.y, mn2 = c.x, mx2 = c.y;
    #pragma unroll
    for (int off = 32; off; off >>= 1) {
        mn0 = fminf(mn0, __shfl_down(mn0, off, 64));
        mx0 = fmaxf(mx0, __shfl_down(mx0, off, 64));
        mn1 = fminf(mn1, __shfl_down(mn1, off, 64));
        mx1 = fmaxf(mx1, __shfl_down(mx1, off, 64));
        mn2 = fminf(mn2, __shfl_down(mn2, off, 64));
        mx2 = fmaxf(mx2, __shfl_down(mx2, off, 64));
    }
    if ((tid & 63) == 0) {
        int w = tid >> 6;
        swred[w][0] = mn0; swred[w][1] = mx0; swred[w][2] = mn1;
        swred[w][3] = mx1; swred[w][4] = mn2; swred[w][5] = mx2;
    }
    __syncthreads();
    mn0 = fminf(fminf(swred[0][0], swred[1][0]), fminf(swred[2][0], swred[3][0]));
    mx0 = fmaxf(fmaxf(swred[0][1], swred[1][1]), fmaxf(swred[2][1], swred[3][1]));
    mn1 = fminf(fminf(swred[0][2], swred[1][2]), fminf(swred[2][2], swred[3][2]));
    mx1 = fmaxf(fmaxf(swred[0][3], swred[1][3]), fmaxf(swred[2][3], swred[3][3]));
    mn2 = fminf(fminf(swred[0][4], swred[1][4]), fminf(swred[2][4], swred[3][4]));
    mx2 = fmaxf(fmaxf(swred[0][5], swred[1][5]), fmaxf(swred[2][5], swred[3][5]));
    xmn = mn0; xinv = 1.0f / (mx0 - mn0);
    tmn = mn1; tinv = 1.0f / (mx1 - mn1);
    dmn = mn2; dinv = 1.0f / (mx2 - mn2);
    __syncthreads();
}

// ================= K2: everything else (main items + softhist + final) ======
__global__ __launch_bounds__(NTHR) void k_work(
        const float* __restrict__ x, const float* __restrict__ tg,
        const float* __restrict__ dp, float* __restrict__ wsf,
        float* __restrict__ out)
{
    __shared__ float smem[SMEMF];
    __shared__ float swred[4][8];
    __shared__ int sbc[2];
    __shared__ float s8[8];
    const int tid = threadIdx.x, bid = blockIdx.x;
    int* ctr = (int*)wsf + WS_CTR;

    float xmn, xinv, tmn, tinv, dmn, dinv;
    reduce_minmax(wsf, swred, tid, xmn, xinv, tmn, tinv, dmn, dinv);

    bool isHist = (bid < NHIST);
    if (isHist) {
        // -------- hist + depth chunk (bid = chunk id) --------
        int c = bid;
        int* lh = (int*)smem;
        for (int i = tid; i < K_FINE; i += NTHR) lh[i] = 0;
        __syncthreads();
        int batch = c / NHC, chunk = c % NHC;
        const float4* x4 = (const float4*)x  + (size_t)batch * (HW / 4) + chunk * 1536;
        const float4* d4 = (const float4*)dp + (size_t)batch * (HW / 4) + chunk * 1536;
        float dsum = 0.f;
        for (int i = tid; i < 1536; i += NTHR) {
            float4 xv = x4[i], dv = d4[i];
            float o0 = (xv.x - xmn) * xinv, o1 = (xv.y - xmn) * xinv;
            float o2 = (xv.z - xmn) * xinv, o3 = (xv.w - xmn) * xinv;
            dsum += o0 * ((dv.x - dmn) * dinv) + o1 * ((dv.y - dmn) * dinv)
                  + o2 * ((dv.z - dmn) * dinv) + o3 * ((dv.w - dmn) * dinv);
            int j0 = min(K_FINE - 1, max(0, (int)(o0 * K_FINE)));
            int j1 = min(K_FINE - 1, max(0, (int)(o1 * K_FINE)));
            int j2 = min(K_FINE - 1, max(0, (int)(o2 * K_FINE)));
            int j3 = min(K_FINE - 1, max(0, (int)(o3 * K_FINE)));
            atomicAdd(lh + j0, 1); atomicAdd(lh + j1, 1);
            atomicAdd(lh + j2, 1); atomicAdd(lh + j3, 1);
        }
        __syncthreads();
        int* ch = (int*)wsf + WS_CHIST + c * K_FINE;
        for (int i = tid; i < K_FINE; i += NTHR) ch[i] = lh[i];
        #pragma unroll
        for (int off = 32; off; off >>= 1) dsum += __shfl_down(dsum, off, 64);
        if ((tid & 63) == 0) swred[tid >> 6][6] = dsum;
        __syncthreads();
        if (tid == 0)
            wsf[WS_DEPTH + c] = swred[0][6] + swred[1][6] + swred[2][6] + swred[3][6];
    } else {
        // -------- SSIM tile (32x32 out, 42x42 halo, two-pass moments) ------
        int tileId = bid - NHIST;
        float g[11];
        {
            float s = 0.f;
            #pragma unroll
            for (int i = 0; i < 11; i++) {
                float dd = (float)(i - 5);
                g[i] = expf(-dd * dd / 4.5f);
                s += g[i];
            }
            float is = 1.0f / s;
            #pragma unroll
            for (int i = 0; i < 11; i++) g[i] *= is;
        }
        float* sO  = smem;                 // [42][43]
        float* sI  = smem + 42 * 43;
        float* hr0 = smem + 2 * 42 * 43;   // [42][33] x3
        float* hr1 = hr0 + HRS;
        float* hr2 = hr1 + HRS;
        int img = tileId / 144;
        int tl  = tileId % 144;
        int ty0 = (tl / 12) * 32 - 5;
        int tx0 = (tl % 12) * 32 - 5;
        const float* xb = x  + (size_t)img * HW;
        const float* tb = tg + (size_t)img * HW;
        for (int idx = tid; idx < 42 * 42; idx += NTHR) {
            int rr = idx / 42, cc = idx % 42;
            int gy = ty0 + rr, gx = tx0 + cc;
            float xv = 0.f, tv = 0.f;
            if (gy >= 0 && gy < IMG && gx >= 0 && gx < IMG) {
                int o = gy * IMG + gx;
                xv = (xb[o] - xmn) * xinv;
                tv = (tb[o] - tmn) * tinv;
            }
            sO[rr * 43 + cc] = xv; sI[rr * 43 + cc] = tv;
        }
        __syncthreads();
        // pass A horiz: mu channels
        for (int idx = tid; idx < 42 * 32; idx += NTHR) {
            int rr = idx >> 5, cx = idx & 31;
            const float* rowO = sO + rr * 43 + cx;
            const float* rowI = sI + rr * 43 + cx;
            float so = 0, si = 0;
            #pragma unroll
            for (int d = 0; d < 11; d++) { so += g[d] * rowO[d]; si += g[d] * rowI[d]; }
            hr0[rr * 33 + cx] = so; hr1[rr * 33 + cx] = si;
        }
        __syncthreads();
        // pass A vert: mu1/mu2 into registers (4-row strip per thread)
        const int ox = tid & 31, oy0 = (tid >> 5) << 2;
        float mu1[4], mu2[4];
        {
            float w0[14], w1[14];
            #pragma unroll
            for (int k = 0; k < 14; k++) {
                int hb = (oy0 + k) * 33 + ox;
                w0[k] = hr0[hb]; w1[k] = hr1[hb];
            }
            #pragma unroll
            for (int p = 0; p < 4; p++) {
                float m1 = 0, m2 = 0;
                #pragma unroll
                for (int dy = 0; dy < 11; dy++) {
                    m1 += g[dy] * w0[p + dy];
                    m2 += g[dy] * w1[p + dy];
                }
                mu1[p] = m1; mu2[p] = m2;
            }
        }
        __syncthreads();
        // pass B horiz: second moments
        for (int idx = tid; idx < 42 * 32; idx += NTHR) {
            int rr = idx >> 5, cx = idx & 31;
            const float* rowO = sO + rr * 43 + cx;
            const float* rowI = sI + rr * 43 + cx;
            float soo = 0, sii = 0, soi = 0;
            #pragma unroll
            for (int d = 0; d < 11; d++) {
                float o = rowO[d], ii = rowI[d], w = g[d];
                soo += w * o * o; sii += w * ii * ii; soi += w * o * ii;
            }
            int hb = rr * 33 + cx;
            hr0[hb] = soo; hr1[hb] = sii; hr2[hb] = soi;
        }
        __syncthreads();
        // pass B vert + formula
        const float C1 = 1e-4f, C2 = 9e-4f;
        float lsum = 0.f;
        {
            float w0[14], w1[14], w2[14];
            #pragma unroll
            for (int k = 0; k < 14; k++) {
                int hb = (oy0 + k) * 33 + ox;
                w0[k] = hr0[hb]; w1[k] = hr1[hb]; w2[k] = hr2[hb];
            }
            #pragma unroll
            for (int p = 0; p < 4; p++) {
                float m11 = 0, m22 = 0, m12 = 0;
                #pragma unroll
                for (int dy = 0; dy < 11; dy++) {
                    float w = g[dy];
                    m11 += w * w0[p + dy];
                    m22 += w * w1[p + dy];
                    m12 += w * w2[p + dy];
                }
                float mu1s = mu1[p] * mu1[p], mu2s = mu2[p] * mu2[p];
                float mu12 = mu1[p] * mu2[p];
                float s1 = m11 - mu1s, s2 = m22 - mu2s, s12 = m12 - mu12;
                lsum += ((2.f * mu12 + C1) * (2.f * s12 + C2))
                      / ((mu1s + mu2s + C1) * (s1 + s2 + C2));
            }
        }
        #pragma unroll
        for (int off = 32; off; off >>= 1) lsum += __shfl_down(lsum, off, 64);
        if ((tid & 63) == 0) swred[tid >> 6][6] = lsum;
        __syncthreads();
        if (tid == 0)
            wsf[WS_SSIM + tileId] = swred[0][6] + swred[1][6] + swred[2][6] + swred[3][6];
    }

    // ---- epilogue: make writes device-visible, take finish ticket ----
    __threadfence();          // every thread: release its global stores
    __syncthreads();
    if (tid == 0) {
        if (isHist) atomicAdd(ctr + CTR_HIST, 1);
        sbc[0] = atomicAdd(ctr + CTR_FIN, 1);
    }
    __syncthreads();
    int rank = sbc[0];
    if (rank < TOTAL - NSOFT) return;

    // ---- softhist item (last 256 finishers) ----
    int srank = rank - (TOTAL - NSOFT);
    if (tid == 0) spin_geq(ctr + CTR_HIST, NHIST);
    __syncthreads();
    __threadfence();          // acquire: chunk hists visible
    {
        int* lh = (int*)smem;
        int batch = srank >> 5;
        const int* base = (const int*)wsf + WS_CHIST + batch * NHC * K_FINE;
        int acc[8];
        #pragma unroll
        for (int k = 0; k < 8; k++) acc[k] = 0;
        for (int c = 0; c < NHC; c++) {
            #pragma unroll
            for (int k = 0; k < 8; k++)
                acc[k] += base[c * K_FINE + tid + k * 256];
        }
        #pragma unroll
        for (int k = 0; k < 8; k++) lh[tid + k * 256] = acc[k];
        __syncthreads();
        int binLocal = tid >> 5, slice = tid & 31;
        int bin = (srank & 31) * 8 + binLocal;
        const float delta = 1.0f / 256.0f;
        const float r   = expf(3.0f * delta);
        const float rm1 = r - 1.0f;
        const float c32 = expf(-3.0f * 32.0f / (float)K_FINE);
        float L = (float)bin * delta;
        float u = expf(3.0f * (L - ((float)slice + 0.5f) * (1.0f / (float)K_FINE)));
        float h = 0.f;
        #pragma unroll 4
        for (int j = slice; j < K_FINE; j += 32) {
            float cnt = (float)lh[j];
            float t1 = 1.0f + u;
            float t2 = fmaf(u, r, 1.0f);
            h = fmaf(cnt * (u * rm1), __builtin_amdgcn_rcpf(t1 * t2), h);
            u *= c32;
        }
        #pragma unroll
        for (int off = 16; off; off >>= 1) h += __shfl_down(h, off, 32);
        if (slice == 0) s8[binLocal] = h;
        __syncthreads();
        if (tid == 0) {
            float hl = 0.f;
            #pragma unroll
            for (int b = 0; b < 8; b++) {
                float hh = s8[b];
                hl += (hh > 0.f) ? hh * logf(hh) : 0.f;
            }
            wsf[WS_UNIF + srank] = hl;
            __threadfence();
            sbc[1] = atomicAdd(ctr + CTR_SOFT, 1);
        }
    }
    __syncthreads();
    if (sbc[1] != NSOFT - 1) return;

    // ---- final combine (the 256th softhist finisher) ----
    if (tid == 0) spin_geq(ctr + CTR_FIN, TOTAL);
    __syncthreads();
    __threadfence();
    {
        float a = 0.f, bsum = 0.f, c = 0.f;
        for (int i = tid; i < NHIST; i += NTHR) a    += wsf[WS_DEPTH + i];
        for (int i = tid; i < NTILE; i += NTHR) bsum += wsf[WS_SSIM + i];
        for (int i = tid; i < NSOFT; i += NTHR) c    += wsf[WS_UNIF + i];
        float* ra = smem; float* rb = ra + 256; float* rc = rb + 256;
        ra[tid] = a; rb[tid] = bsum; rc[tid] = c;
        __syncthreads();
        for (int s = 128; s; s >>= 1) {
            if (tid < s) {
                ra[tid] += ra[tid + s];
                rb[tid] += rb[tid + s];
                rc[tid] += rc[tid + s];
            }
            __syncthreads();
        }
        if (tid == 0) {
            float uniform  = rc[0] / 8.0f;
            float depthL   = ra[0] / 8.0f;
            float ssimMean = rb[0] / (float)N1;
            out[0] = 1e-6f * uniform + 1e-5f * depthL + (1.0f - ssimMean);
        }
    }
}

extern "C" void kernel_launch(void* const* d_in, const int* in_sizes, int n_in,
                              void* d_out, int out_size, void* d_ws, size_t ws_size,
                              hipStream_t stream) {
    const float* x  = (const float*)d_in[0];
    const float* tg = (const float*)d_in[1];
    const float* dp = (const float*)d_in[2];
    float* wsf = (float*)d_ws;
    float* out = (float*)d_out;
    hipLaunchKernelGGL(k_minmax, dim3(256),   dim3(NTHR), 0, stream, x, tg, dp, wsf);
    hipLaunchKernelGGL(k_work,   dim3(TOTAL), dim3(NTHR), 0, stream, x, tg, dp, wsf, out);
}

// Round 7
// 51.150 us; speedup vs baseline: 3.8158x; 3.8158x over previous
//
#include <hip/hip_runtime.h>
#include <math.h>

#define NTHR 256
#define K_FINE 2048
#define HW 147456          // 384*384
#define N1 1179648         // 8*HW
#define IMG 384
#define NHC 24             // hist chunks per batch
#define NHIST 192          // 8*24
#define NTILE 1152         // 8 * 144 ssim tiles
#define TOTAL (NTILE + NHIST)   // 1344 blocks in k_work
#define NSOFT 256

// ws word offsets
#define WS_PMM   0                          // [3][256][2] floats
#define WS_CTR   1536                       // counters (8 ints)
#define WS_HIST  1544                       // 8*2048 ints (global atomic hist)
#define WS_DEPTH (WS_HIST + 8*K_FINE)       // 192 floats
#define WS_SSIM  (WS_DEPTH + NHIST)         // 1152 floats
#define WS_UNIF  (WS_SSIM + NTILE)          // 256 floats

#define CTR_FIN  0
#define CTR_HIST 1
#define CTR_SOFT 2

#define HRS (42*33)
#define SMEMF (42*43*2 + 3*HRS)             // 7770 floats = 31.1 KB

#define AGENT __HIP_MEMORY_SCOPE_AGENT

__device__ __forceinline__ void spin_geq(int* p, int target) {
    while (__hip_atomic_load(p, __ATOMIC_ACQUIRE, AGENT) < target)
        __builtin_amdgcn_s_sleep(8);
}
__device__ __forceinline__ void st_agent(float* p, float v) {
    __hip_atomic_store(p, v, __ATOMIC_RELAXED, AGENT);
}
__device__ __forceinline__ float ld_agent_f(const float* p) {
    return __hip_atomic_load((float*)p, __ATOMIC_RELAXED, AGENT);
}
__device__ __forceinline__ int ld_agent_i(const int* p) {
    return __hip_atomic_load((int*)p, __ATOMIC_RELAXED, AGENT);
}
__device__ __forceinline__ void drain_vmem() {
    asm volatile("s_waitcnt vmcnt(0)" ::: "memory");
}

// ================= K1: per-block min/max partials; zero hist+counters =======
__global__ __launch_bounds__(NTHR) void k_minmax(
        const float* __restrict__ x, const float* __restrict__ tg,
        const float* __restrict__ dp, float* __restrict__ wsf)
{
    __shared__ float swred[4][8];
    const int tid = threadIdx.x, bid = blockIdx.x;
    const float4* x4 = (const float4*)x  + bid * 1152;
    const float4* t4 = (const float4*)tg + bid * 1152;
    const float4* d4 = (const float4*)dp + bid * 1152;
    float mn0 = 3.4e38f, mx0 = -3.4e38f;
    float mn1 = 3.4e38f, mx1 = -3.4e38f;
    float mn2 = 3.4e38f, mx2 = -3.4e38f;
    for (int i = tid; i < 1152; i += NTHR) {
        float4 v = x4[i];
        mn0 = fminf(mn0, fminf(fminf(v.x, v.y), fminf(v.z, v.w)));
        mx0 = fmaxf(mx0, fmaxf(fmaxf(v.x, v.y), fmaxf(v.z, v.w)));
        v = t4[i];
        mn1 = fminf(mn1, fminf(fminf(v.x, v.y), fminf(v.z, v.w)));
        mx1 = fmaxf(mx1, fmaxf(fmaxf(v.x, v.y), fmaxf(v.z, v.w)));
        v = d4[i];
        mn2 = fminf(mn2, fminf(fminf(v.x, v.y), fminf(v.z, v.w)));
        mx2 = fmaxf(mx2, fmaxf(fmaxf(v.x, v.y), fmaxf(v.z, v.w)));
    }
    #pragma unroll
    for (int off = 32; off; off >>= 1) {
        mn0 = fminf(mn0, __shfl_down(mn0, off, 64));
        mx0 = fmaxf(mx0, __shfl_down(mx0, off, 64));
        mn1 = fminf(mn1, __shfl_down(mn1, off, 64));
        mx1 = fmaxf(mx1, __shfl_down(mx1, off, 64));
        mn2 = fminf(mn2, __shfl_down(mn2, off, 64));
        mx2 = fmaxf(mx2, __shfl_down(mx2, off, 64));
    }
    if ((tid & 63) == 0) {
        int w = tid >> 6;
        swred[w][0] = mn0; swred[w][1] = mx0; swred[w][2] = mn1;
        swred[w][3] = mx1; swred[w][4] = mn2; swred[w][5] = mx2;
    }
    __syncthreads();
    if (tid == 0) {
        #pragma unroll
        for (int w = 1; w < 4; w++) {
            swred[0][0] = fminf(swred[0][0], swred[w][0]);
            swred[0][1] = fmaxf(swred[0][1], swred[w][1]);
            swred[0][2] = fminf(swred[0][2], swred[w][2]);
            swred[0][3] = fmaxf(swred[0][3], swred[w][3]);
            swred[0][4] = fminf(swred[0][4], swred[w][4]);
            swred[0][5] = fmaxf(swred[0][5], swred[w][5]);
        }
        wsf[WS_PMM +        bid * 2]     = swred[0][0];
        wsf[WS_PMM +        bid * 2 + 1] = swred[0][1];
        wsf[WS_PMM + 512  + bid * 2]     = swred[0][2];
        wsf[WS_PMM + 512  + bid * 2 + 1] = swred[0][3];
        wsf[WS_PMM + 1024 + bid * 2]     = swred[0][4];
        wsf[WS_PMM + 1024 + bid * 2 + 1] = swred[0][5];
    }
    if (tid < 64) ((int*)wsf)[WS_HIST + bid * 64 + tid] = 0;
    if (bid == 0 && tid < 8) ((int*)wsf)[WS_CTR + tid] = 0;
}

// helper: per-block redundant global min/max reduce from partials
__device__ __forceinline__ void reduce_minmax(
        const float* __restrict__ wsf, float swred[4][8], int tid,
        float& xmn, float& xinv, float& tmn, float& tinv, float& dmn, float& dinv)
{
    const float2* pm = (const float2*)&wsf[WS_PMM];
    float2 a = pm[tid], b = pm[256 + tid], c = pm[512 + tid];
    float mn0 = a.x, mx0 = a.y, mn1 = b.x, mx1 = b.y, mn2 = c.x, mx2 = c.y;
    #pragma unroll
    for (int off = 32; off; off >>= 1) {
        mn0 = fminf(mn0, __shfl_down(mn0, off, 64));
        mx0 = fmaxf(mx0, __shfl_down(mx0, off, 64));
        mn1 = fminf(mn1, __shfl_down(mn1, off, 64));
        mx1 = fmaxf(mx1, __shfl_down(mx1, off, 64));
        mn2 = fminf(mn2, __shfl_down(mn2, off, 64));
        mx2 = fmaxf(mx2, __shfl_down(mx2, off, 64));
    }
    if ((tid & 63) == 0) {
        int w = tid >> 6;
        swred[w][0] = mn0; swred[w][1] = mx0; swred[w][2] = mn1;
        swred[w][3] = mx1; swred[w][4] = mn2; swred[w][5] = mx2;
    }
    __syncthreads();
    mn0 = fminf(fminf(swred[0][0], swred[1][0]), fminf(swred[2][0], swred[3][0]));
    mx0 = fmaxf(fmaxf(swred[0][1], swred[1][1]), fmaxf(swred[2][1], swred[3][1]));
    mn1 = fminf(fminf(swred[0][2], swred[1][2]), fminf(swred[2][2], swred[3][2]));
    mx1 = fmaxf(fmaxf(swred[0][3], swred[1][3]), fmaxf(swred[2][3], swred[3][3]));
    mn2 = fminf(fminf(swred[0][4], swred[1][4]), fminf(swred[2][4], swred[3][4]));
    mx2 = fmaxf(fmaxf(swred[0][5], swred[1][5]), fmaxf(swred[2][5], swred[3][5]));
    xmn = mn0; xinv = 1.0f / (mx0 - mn0);
    tmn = mn1; tinv = 1.0f / (mx1 - mn1);
    dmn = mn2; dinv = 1.0f / (mx2 - mn2);
    __syncthreads();
}

// ================= K2: main items + softhist + final (atomic handoff) =======
__global__ __launch_bounds__(NTHR) void k_work(
        const float* __restrict__ x, const float* __restrict__ tg,
        const float* __restrict__ dp, float* __restrict__ wsf,
        float* __restrict__ out)
{
    __shared__ float smem[SMEMF];
    __shared__ float swred[4][8];
    __shared__ int sbLast;
    __shared__ float s8[8];
    const int tid = threadIdx.x, bid = blockIdx.x;
    int* ctr = (int*)wsf + WS_CTR;

    float xmn, xinv, tmn, tinv, dmn, dinv;
    reduce_minmax(wsf, swred, tid, xmn, xinv, tmn, tinv, dmn, dinv);

    const bool isHist = (bid < NHIST);
    if (isHist) {
        // -------- hist + depth chunk (bid = chunk id) --------
        int c = bid;
        int* lh = (int*)smem;
        for (int i = tid; i < K_FINE; i += NTHR) lh[i] = 0;
        __syncthreads();
        int batch = c / NHC, chunk = c % NHC;
        const float4* x4 = (const float4*)x  + (size_t)batch * (HW / 4) + chunk * 1536;
        const float4* d4 = (const float4*)dp + (size_t)batch * (HW / 4) + chunk * 1536;
        float dsum = 0.f;
        for (int i = tid; i < 1536; i += NTHR) {
            float4 xv = x4[i], dv = d4[i];
            float o0 = (xv.x - xmn) * xinv, o1 = (xv.y - xmn) * xinv;
            float o2 = (xv.z - xmn) * xinv, o3 = (xv.w - xmn) * xinv;
            dsum += o0 * ((dv.x - dmn) * dinv) + o1 * ((dv.y - dmn) * dinv)
                  + o2 * ((dv.z - dmn) * dinv) + o3 * ((dv.w - dmn) * dinv);
            int j0 = min(K_FINE - 1, max(0, (int)(o0 * K_FINE)));
            int j1 = min(K_FINE - 1, max(0, (int)(o1 * K_FINE)));
            int j2 = min(K_FINE - 1, max(0, (int)(o2 * K_FINE)));
            int j3 = min(K_FINE - 1, max(0, (int)(o3 * K_FINE)));
            atomicAdd(lh + j0, 1); atomicAdd(lh + j1, 1);
            atomicAdd(lh + j2, 1); atomicAdd(lh + j3, 1);
        }
        __syncthreads();
        int* gh = (int*)wsf + WS_HIST + batch * K_FINE;
        for (int i = tid; i < K_FINE; i += NTHR) {
            int v = lh[i];
            if (v) atomicAdd(gh + i, v);    // device-coherent
        }
        #pragma unroll
        for (int off = 32; off; off >>= 1) dsum += __shfl_down(dsum, off, 64);
        if ((tid & 63) == 0) swred[tid >> 6][6] = dsum;
        __syncthreads();
        if (tid == 0)
            st_agent(&wsf[WS_DEPTH + c],
                     swred[0][6] + swred[1][6] + swred[2][6] + swred[3][6]);
    } else {
        // -------- SSIM tile (32x32 out, 42x42 halo, two-pass moments) ------
        int tileId = bid - NHIST;
        float g[11];
        {
            float s = 0.f;
            #pragma unroll
            for (int i = 0; i < 11; i++) {
                float dd = (float)(i - 5);
                g[i] = expf(-dd * dd / 4.5f);
                s += g[i];
            }
            float is = 1.0f / s;
            #pragma unroll
            for (int i = 0; i < 11; i++) g[i] *= is;
        }
        float* sO  = smem;                 // [42][43]
        float* sI  = smem + 42 * 43;
        float* hr0 = smem + 2 * 42 * 43;   // [42][33] x3
        float* hr1 = hr0 + HRS;
        float* hr2 = hr1 + HRS;
        int img = tileId / 144;
        int tl  = tileId % 144;
        int ty0 = (tl / 12) * 32 - 5;
        int tx0 = (tl % 12) * 32 - 5;
        const float* xb = x  + (size_t)img * HW;
        const float* tb = tg + (size_t)img * HW;
        for (int idx = tid; idx < 42 * 42; idx += NTHR) {
            int rr = idx / 42, cc = idx % 42;
            int gy = ty0 + rr, gx = tx0 + cc;
            float xv = 0.f, tv = 0.f;
            if (gy >= 0 && gy < IMG && gx >= 0 && gx < IMG) {
                int o = gy * IMG + gx;
                xv = (xb[o] - xmn) * xinv;
                tv = (tb[o] - tmn) * tinv;
            }
            sO[rr * 43 + cc] = xv; sI[rr * 43 + cc] = tv;
        }
        __syncthreads();
        for (int idx = tid; idx < 42 * 32; idx += NTHR) {
            int rr = idx >> 5, cx = idx & 31;
            const float* rowO = sO + rr * 43 + cx;
            const float* rowI = sI + rr * 43 + cx;
            float so = 0, si = 0;
            #pragma unroll
            for (int d = 0; d < 11; d++) { so += g[d] * rowO[d]; si += g[d] * rowI[d]; }
            hr0[rr * 33 + cx] = so; hr1[rr * 33 + cx] = si;
        }
        __syncthreads();
        const int ox = tid & 31, oy0 = (tid >> 5) << 2;
        float mu1[4], mu2[4];
        {
            float w0[14], w1[14];
            #pragma unroll
            for (int k = 0; k < 14; k++) {
                int hb = (oy0 + k) * 33 + ox;
                w0[k] = hr0[hb]; w1[k] = hr1[hb];
            }
            #pragma unroll
            for (int p = 0; p < 4; p++) {
                float m1 = 0, m2 = 0;
                #pragma unroll
                for (int dy = 0; dy < 11; dy++) {
                    m1 += g[dy] * w0[p + dy];
                    m2 += g[dy] * w1[p + dy];
                }
                mu1[p] = m1; mu2[p] = m2;
            }
        }
        __syncthreads();
        for (int idx = tid; idx < 42 * 32; idx += NTHR) {
            int rr = idx >> 5, cx = idx & 31;
            const float* rowO = sO + rr * 43 + cx;
            const float* rowI = sI + rr * 43 + cx;
            float soo = 0, sii = 0, soi = 0;
            #pragma unroll
            for (int d = 0; d < 11; d++) {
                float o = rowO[d], ii = rowI[d], w = g[d];
                soo += w * o * o; sii += w * ii * ii; soi += w * o * ii;
            }
            int hb = rr * 33 + cx;
            hr0[hb] = soo; hr1[hb] = sii; hr2[hb] = soi;
        }
        __syncthreads();
        const float C1 = 1e-4f, C2 = 9e-4f;
        float lsum = 0.f;
        {
            float w0[14], w1[14], w2[14];
            #pragma unroll
            for (int k = 0; k < 14; k++) {
                int hb = (oy0 + k) * 33 + ox;
                w0[k] = hr0[hb]; w1[k] = hr1[hb]; w2[k] = hr2[hb];
            }
            #pragma unroll
            for (int p = 0; p < 4; p++) {
                float m11 = 0, m22 = 0, m12 = 0;
                #pragma unroll
                for (int dy = 0; dy < 11; dy++) {
                    float w = g[dy];
                    m11 += w * w0[p + dy];
                    m22 += w * w1[p + dy];
                    m12 += w * w2[p + dy];
                }
                float mu1s = mu1[p] * mu1[p], mu2s = mu2[p] * mu2[p];
                float mu12 = mu1[p] * mu2[p];
                float s1 = m11 - mu1s, s2 = m22 - mu2s, s12 = m12 - mu12;
                lsum += ((2.f * mu12 + C1) * (2.f * s12 + C2))
                      / ((mu1s + mu2s + C1) * (s1 + s2 + C2));
            }
        }
        #pragma unroll
        for (int off = 32; off; off >>= 1) lsum += __shfl_down(lsum, off, 64);
        if ((tid & 63) == 0) swred[tid >> 6][6] = lsum;
        __syncthreads();
        if (tid == 0)
            st_agent(&wsf[WS_SSIM + tileId],
                     swred[0][6] + swred[1][6] + swred[2][6] + swred[3][6]);
    }

    // ---- epilogue: drain this wave's vmem, then ticket (no fences) ----
    drain_vmem();
    __syncthreads();           // all waves drained (syncthreads also drains)
    if (tid == 0) {
        if (isHist) __hip_atomic_fetch_add(ctr + CTR_HIST, 1, __ATOMIC_RELAXED, AGENT);
        __hip_atomic_fetch_add(ctr + CTR_FIN, 1, __ATOMIC_RELAXED, AGENT);
    }

    // ---- softhist: statically blocks 192..447 ----
    if (bid < NHIST || bid >= NHIST + NSOFT) return;
    int srank = bid - NHIST;
    if (tid == 0) spin_geq(ctr + CTR_HIST, NHIST);
    __syncthreads();
    {
        int* lh = (int*)smem;
        int batch = srank >> 5;
        const int* gh = (const int*)wsf + WS_HIST + batch * K_FINE;
        #pragma unroll
        for (int k = 0; k < 8; k++)
            lh[tid + k * 256] = ld_agent_i(gh + tid + k * 256);
        __syncthreads();
        int binLocal = tid >> 5, slice = tid & 31;
        int bin = (srank & 31) * 8 + binLocal;
        const float delta = 1.0f / 256.0f;
        const float r   = expf(3.0f * delta);
        const float rm1 = r - 1.0f;
        const float c32 = expf(-3.0f * 32.0f / (float)K_FINE);
        float L = (float)bin * delta;
        float u = expf(3.0f * (L - ((float)slice + 0.5f) * (1.0f / (float)K_FINE)));
        float h = 0.f;
        #pragma unroll 4
        for (int j = slice; j < K_FINE; j += 32) {
            float cnt = (float)lh[j];
            float t1 = 1.0f + u;
            float t2 = fmaf(u, r, 1.0f);
            h = fmaf(cnt * (u * rm1), __builtin_amdgcn_rcpf(t1 * t2), h);
            u *= c32;
        }
        #pragma unroll
        for (int off = 16; off; off >>= 1) h += __shfl_down(h, off, 32);
        if (slice == 0) s8[binLocal] = h;
        __syncthreads();
        if (tid == 0) {
            float hl = 0.f;
            #pragma unroll
            for (int b = 0; b < 8; b++) {
                float hh = s8[b];
                hl += (hh > 0.f) ? hh * logf(hh) : 0.f;
            }
            st_agent(&wsf[WS_UNIF + srank], hl);
            drain_vmem();
            int old = __hip_atomic_fetch_add(ctr + CTR_SOFT, 1, __ATOMIC_RELAXED, AGENT);
            sbLast = (old == NSOFT - 1);
        }
    }
    __syncthreads();
    if (!sbLast) return;

    // ---- final combine (last softhist finisher) ----
    if (tid == 0) spin_geq(ctr + CTR_FIN, TOTAL);
    __syncthreads();
    {
        float a = 0.f, bsum = 0.f, c = 0.f;
        for (int i = tid; i < NHIST; i += NTHR) a    += ld_agent_f(&wsf[WS_DEPTH + i]);
        for (int i = tid; i < NTILE; i += NTHR) bsum += ld_agent_f(&wsf[WS_SSIM + i]);
        for (int i = tid; i < NSOFT; i += NTHR) c    += ld_agent_f(&wsf[WS_UNIF + i]);
        float* ra = smem; float* rb = ra + 256; float* rc = rb + 256;
        ra[tid] = a; rb[tid] = bsum; rc[tid] = c;
        __syncthreads();
        for (int s = 128; s; s >>= 1) {
            if (tid < s) {
                ra[tid] += ra[tid + s];
                rb[tid] += rb[tid + s];
                rc[tid] += rc[tid + s];
            }
            __syncthreads();
        }
        if (tid == 0) {
            float uniform  = rc[0] / 8.0f;
            float depthL   = ra[0] / 8.0f;
            float ssimMean = rb[0] / (float)N1;
            out[0] = 1e-6f * uniform + 1e-5f * depthL + (1.0f - ssimMean);
        }
    }
}

extern "C" void kernel_launch(void* const* d_in, const int* in_sizes, int n_in,
                              void* d_out, int out_size, void* d_ws, size_t ws_size,
                              hipStream_t stream) {
    const float* x  = (const float*)d_in[0];
    const float* tg = (const float*)d_in[1];
    const float* dp = (const float*)d_in[2];
    float* wsf = (float*)d_ws;
    float* out = (float*)d_out;
    hipLaunchKernelGGL(k_minmax, dim3(256),   dim3(NTHR), 0, stream, x, tg, dp, wsf);
    hipLaunchKernelGGL(k_work,   dim3(TOTAL), dim3(NTHR), 0, stream, x, tg, dp, wsf, out);
}

// Round 8
// 39.738 us; speedup vs baseline: 4.9116x; 1.2872x over previous
//
#include <hip/hip_runtime.h>
#include <math.h>

#define NTHR 256
#define K_FINE 2048
#define HW 147456          // 384*384
#define N1 1179648         // 8*HW
#define IMG 384
#define NHC 16             // hist chunks per batch
#define NCHUNK 128         // 8*16
#define NTILE 1152         // 8 * 144 ssim tiles
#define TOTAL (NTILE + NCHUNK)   // 1280 = 256 CUs * 5 blocks
#define NSOFT 256

// ws word offsets
#define WS_PMM  0                       // [3][256][2] floats (min,max partials)
#define WS_SUM  1536                    // [3][256] floats: Sxd, Sx, Sd partials
#define WS_CTR  2304                    // ticket (8 ints)
#define WS_HIST 2312                    // 8*2048 ints (global atomic hist)
#define WS_SSIM (WS_HIST + 8*K_FINE)    // 1152 floats
#define WS_UNIF (WS_SSIM + NTILE)       // 256 floats

#define HRS (42*33)
#define SMEMF (42*43*2 + 3*HRS)         // 7770 floats = 31.1 KB

// ================= K1: min/max + raw-sum partials; zero hist+ticket =========
__global__ __launch_bounds__(NTHR) void k_minmax(
        const float* __restrict__ x, const float* __restrict__ tg,
        const float* __restrict__ dp, float* __restrict__ wsf)
{
    __shared__ float swred[4][12];
    const int tid = threadIdx.x, bid = blockIdx.x;
    const float4* x4 = (const float4*)x  + bid * 1152;
    const float4* t4 = (const float4*)tg + bid * 1152;
    const float4* d4 = (const float4*)dp + bid * 1152;
    float mn0 = 3.4e38f, mx0 = -3.4e38f;
    float mn1 = 3.4e38f, mx1 = -3.4e38f;
    float mn2 = 3.4e38f, mx2 = -3.4e38f;
    float sx = 0.f, sd = 0.f, sxd = 0.f;
    for (int i = tid; i < 1152; i += NTHR) {
        float4 a = x4[i], b = t4[i], d = d4[i];
        mn0 = fminf(mn0, fminf(fminf(a.x, a.y), fminf(a.z, a.w)));
        mx0 = fmaxf(mx0, fmaxf(fmaxf(a.x, a.y), fmaxf(a.z, a.w)));
        mn1 = fminf(mn1, fminf(fminf(b.x, b.y), fminf(b.z, b.w)));
        mx1 = fmaxf(mx1, fmaxf(fmaxf(b.x, b.y), fmaxf(b.z, b.w)));
        mn2 = fminf(mn2, fminf(fminf(d.x, d.y), fminf(d.z, d.w)));
        mx2 = fmaxf(mx2, fmaxf(fmaxf(d.x, d.y), fmaxf(d.z, d.w)));
        sx += (a.x + a.y) + (a.z + a.w);
        sd += (d.x + d.y) + (d.z + d.w);
        sxd = fmaf(a.x, d.x, fmaf(a.y, d.y, fmaf(a.z, d.z, fmaf(a.w, d.w, sxd))));
    }
    #pragma unroll
    for (int off = 32; off; off >>= 1) {
        mn0 = fminf(mn0, __shfl_down(mn0, off, 64));
        mx0 = fmaxf(mx0, __shfl_down(mx0, off, 64));
        mn1 = fminf(mn1, __shfl_down(mn1, off, 64));
        mx1 = fmaxf(mx1, __shfl_down(mx1, off, 64));
        mn2 = fminf(mn2, __shfl_down(mn2, off, 64));
        mx2 = fmaxf(mx2, __shfl_down(mx2, off, 64));
        sx  += __shfl_down(sx,  off, 64);
        sd  += __shfl_down(sd,  off, 64);
        sxd += __shfl_down(sxd, off, 64);
    }
    if ((tid & 63) == 0) {
        int w = tid >> 6;
        swred[w][0] = mn0; swred[w][1] = mx0; swred[w][2] = mn1;
        swred[w][3] = mx1; swred[w][4] = mn2; swred[w][5] = mx2;
        swred[w][6] = sxd; swred[w][7] = sx;  swred[w][8] = sd;
    }
    __syncthreads();
    if (tid == 0) {
        #pragma unroll
        for (int w = 1; w < 4; w++) {
            swred[0][0] = fminf(swred[0][0], swred[w][0]);
            swred[0][1] = fmaxf(swred[0][1], swred[w][1]);
            swred[0][2] = fminf(swred[0][2], swred[w][2]);
            swred[0][3] = fmaxf(swred[0][3], swred[w][3]);
            swred[0][4] = fminf(swred[0][4], swred[w][4]);
            swred[0][5] = fmaxf(swred[0][5], swred[w][5]);
            swred[0][6] += swred[w][6];
            swred[0][7] += swred[w][7];
            swred[0][8] += swred[w][8];
        }
        wsf[WS_PMM +        bid * 2]     = swred[0][0];
        wsf[WS_PMM +        bid * 2 + 1] = swred[0][1];
        wsf[WS_PMM + 512  + bid * 2]     = swred[0][2];
        wsf[WS_PMM + 512  + bid * 2 + 1] = swred[0][3];
        wsf[WS_PMM + 1024 + bid * 2]     = swred[0][4];
        wsf[WS_PMM + 1024 + bid * 2 + 1] = swred[0][5];
        wsf[WS_SUM +        bid] = swred[0][6];
        wsf[WS_SUM + 256  + bid] = swred[0][7];
        wsf[WS_SUM + 512  + bid] = swred[0][8];
        if (bid == 0) ((int*)wsf)[WS_CTR] = 0;
    }
    if (tid < 64) ((int*)wsf)[WS_HIST + bid * 64 + tid] = 0;
}

// helper: per-block redundant global min/max reduce from partials
__device__ __forceinline__ void reduce_minmax(
        const float* __restrict__ wsf, float swred[4][12], int tid,
        float& xmn, float& xinv, float& tmn, float& tinv, float& dmn, float& dinv)
{
    const float2* pm = (const float2*)&wsf[WS_PMM];
    float2 a = pm[tid], b = pm[256 + tid], c = pm[512 + tid];
    float mn0 = a.x, mx0 = a.y, mn1 = b.x, mx1 = b.y, mn2 = c.x, mx2 = c.y;
    #pragma unroll
    for (int off = 32; off; off >>= 1) {
        mn0 = fminf(mn0, __shfl_down(mn0, off, 64));
        mx0 = fmaxf(mx0, __shfl_down(mx0, off, 64));
        mn1 = fminf(mn1, __shfl_down(mn1, off, 64));
        mx1 = fmaxf(mx1, __shfl_down(mx1, off, 64));
        mn2 = fminf(mn2, __shfl_down(mn2, off, 64));
        mx2 = fmaxf(mx2, __shfl_down(mx2, off, 64));
    }
    if ((tid & 63) == 0) {
        int w = tid >> 6;
        swred[w][0] = mn0; swred[w][1] = mx0; swred[w][2] = mn1;
        swred[w][3] = mx1; swred[w][4] = mn2; swred[w][5] = mx2;
    }
    __syncthreads();
    mn0 = fminf(fminf(swred[0][0], swred[1][0]), fminf(swred[2][0], swred[3][0]));
    mx0 = fmaxf(fmaxf(swred[0][1], swred[1][1]), fmaxf(swred[2][1], swred[3][1]));
    mn1 = fminf(fminf(swred[0][2], swred[1][2]), fminf(swred[2][2], swred[3][2]));
    mx1 = fmaxf(fmaxf(swred[0][3], swred[1][3]), fmaxf(swred[2][3], swred[3][3]));
    mn2 = fminf(fminf(swred[0][4], swred[1][4]), fminf(swred[2][4], swred[3][4]));
    mx2 = fmaxf(fmaxf(swred[0][5], swred[1][5]), fmaxf(swred[2][5], swred[3][5]));
    xmn = mn0; xinv = 1.0f / (mx0 - mn0);
    tmn = mn1; tinv = 1.0f / (mx1 - mn1);
    dmn = mn2; dinv = 1.0f / (mx2 - mn2);
    __syncthreads();
}

// ================= K2: fused SSIM tiles + hist chunks =======================
__global__ __launch_bounds__(NTHR) void k_work(
        const float* __restrict__ x, const float* __restrict__ tg,
        float* __restrict__ wsf)
{
    __shared__ float smem[SMEMF];
    __shared__ float swred[4][12];
    const int tid = threadIdx.x, bid = blockIdx.x;

    float xmn, xinv, tmn, tinv, dmn, dinv;
    reduce_minmax(wsf, swred, tid, xmn, xinv, tmn, tinv, dmn, dinv);
    (void)dmn; (void)dinv;

    if (bid < NTILE) {
        // -------- SSIM tile (32x32 out, 42x42 halo, two-pass moments) ------
        float g[11];
        {
            float s = 0.f;
            #pragma unroll
            for (int i = 0; i < 11; i++) {
                float dd = (float)(i - 5);
                g[i] = expf(-dd * dd / 4.5f);
                s += g[i];
            }
            float is = 1.0f / s;
            #pragma unroll
            for (int i = 0; i < 11; i++) g[i] *= is;
        }
        float* sO  = smem;                 // [42][43]
        float* sI  = smem + 42 * 43;
        float* hr0 = smem + 2 * 42 * 43;   // [42][33] x3
        float* hr1 = hr0 + HRS;
        float* hr2 = hr1 + HRS;
        int img = bid / 144;
        int tl  = bid % 144;
        int ty0 = (tl / 12) * 32 - 5;
        int tx0 = (tl % 12) * 32 - 5;
        const float* xb = x  + (size_t)img * HW;
        const float* tb = tg + (size_t)img * HW;
        for (int idx = tid; idx < 42 * 42; idx += NTHR) {
            int rr = idx / 42, cc = idx % 42;
            int gy = ty0 + rr, gx = tx0 + cc;
            float xv = 0.f, tv = 0.f;
            if (gy >= 0 && gy < IMG && gx >= 0 && gx < IMG) {
                int o = gy * IMG + gx;
                xv = (xb[o] - xmn) * xinv;
                tv = (tb[o] - tmn) * tinv;
            }
            sO[rr * 43 + cc] = xv; sI[rr * 43 + cc] = tv;
        }
        __syncthreads();
        // pass A horiz: mu channels
        for (int idx = tid; idx < 42 * 32; idx += NTHR) {
            int rr = idx >> 5, cx = idx & 31;
            const float* rowO = sO + rr * 43 + cx;
            const float* rowI = sI + rr * 43 + cx;
            float so = 0, si = 0;
            #pragma unroll
            for (int d = 0; d < 11; d++) { so += g[d] * rowO[d]; si += g[d] * rowI[d]; }
            hr0[rr * 33 + cx] = so; hr1[rr * 33 + cx] = si;
        }
        __syncthreads();
        // pass A vert: mu1/mu2 into registers (4-row strip per thread)
        const int ox = tid & 31, oy0 = (tid >> 5) << 2;
        float mu1[4], mu2[4];
        {
            float w0[14], w1[14];
            #pragma unroll
            for (int k = 0; k < 14; k++) {
                int hb = (oy0 + k) * 33 + ox;
                w0[k] = hr0[hb]; w1[k] = hr1[hb];
            }
            #pragma unroll
            for (int p = 0; p < 4; p++) {
                float m1 = 0, m2 = 0;
                #pragma unroll
                for (int dy = 0; dy < 11; dy++) {
                    m1 += g[dy] * w0[p + dy];
                    m2 += g[dy] * w1[p + dy];
                }
                mu1[p] = m1; mu2[p] = m2;
            }
        }
        __syncthreads();
        // pass B horiz: second moments
        for (int idx = tid; idx < 42 * 32; idx += NTHR) {
            int rr = idx >> 5, cx = idx & 31;
            const float* rowO = sO + rr * 43 + cx;
            const float* rowI = sI + rr * 43 + cx;
            float soo = 0, sii = 0, soi = 0;
            #pragma unroll
            for (int d = 0; d < 11; d++) {
                float o = rowO[d], ii = rowI[d], w = g[d];
                soo += w * o * o; sii += w * ii * ii; soi += w * o * ii;
            }
            int hb = rr * 33 + cx;
            hr0[hb] = soo; hr1[hb] = sii; hr2[hb] = soi;
        }
        __syncthreads();
        // pass B vert + formula
        const float C1 = 1e-4f, C2 = 9e-4f;
        float lsum = 0.f;
        {
            float w0[14], w1[14], w2[14];
            #pragma unroll
            for (int k = 0; k < 14; k++) {
                int hb = (oy0 + k) * 33 + ox;
                w0[k] = hr0[hb]; w1[k] = hr1[hb]; w2[k] = hr2[hb];
            }
            #pragma unroll
            for (int p = 0; p < 4; p++) {
                float m11 = 0, m22 = 0, m12 = 0;
                #pragma unroll
                for (int dy = 0; dy < 11; dy++) {
                    float w = g[dy];
                    m11 += w * w0[p + dy];
                    m22 += w * w1[p + dy];
                    m12 += w * w2[p + dy];
                }
                float mu1s = mu1[p] * mu1[p], mu2s = mu2[p] * mu2[p];
                float mu12 = mu1[p] * mu2[p];
                float s1 = m11 - mu1s, s2 = m22 - mu2s, s12 = m12 - mu12;
                lsum += ((2.f * mu12 + C1) * (2.f * s12 + C2))
                      / ((mu1s + mu2s + C1) * (s1 + s2 + C2));
            }
        }
        #pragma unroll
        for (int off = 32; off; off >>= 1) lsum += __shfl_down(lsum, off, 64);
        if ((tid & 63) == 0) swred[tid >> 6][6] = lsum;
        __syncthreads();
        if (tid == 0)
            wsf[WS_SSIM + bid] = swred[0][6] + swred[1][6] + swred[2][6] + swred[3][6];
    } else {
        // -------- hist chunk (x only; depth folded into k_minmax) --------
        int c = bid - NTILE;
        int* lh = (int*)smem;
        for (int i = tid; i < K_FINE; i += NTHR) lh[i] = 0;
        __syncthreads();
        int batch = c >> 4, chunk = c & 15;
        const float4* x4 = (const float4*)x + (size_t)batch * (HW / 4) + chunk * 2304;
        for (int i = tid; i < 2304; i += NTHR) {
            float4 xv = x4[i];
            float o0 = (xv.x - xmn) * xinv, o1 = (xv.y - xmn) * xinv;
            float o2 = (xv.z - xmn) * xinv, o3 = (xv.w - xmn) * xinv;
            int j0 = min(K_FINE - 1, max(0, (int)(o0 * K_FINE)));
            int j1 = min(K_FINE - 1, max(0, (int)(o1 * K_FINE)));
            int j2 = min(K_FINE - 1, max(0, (int)(o2 * K_FINE)));
            int j3 = min(K_FINE - 1, max(0, (int)(o3 * K_FINE)));
            atomicAdd(lh + j0, 1); atomicAdd(lh + j1, 1);
            atomicAdd(lh + j2, 1); atomicAdd(lh + j3, 1);
        }
        __syncthreads();
        int* gh = (int*)wsf + WS_HIST + batch * K_FINE;
        for (int i = tid; i < K_FINE; i += NTHR) {
            int v = lh[i];
            if (v) atomicAdd(gh + i, v);
        }
    }
}

// ================= K3: soft-hist entropy + last-block final combine =========
__global__ __launch_bounds__(NTHR) void k_soft_final(
        float* __restrict__ wsf, float* __restrict__ out)
{
    __shared__ int lh[K_FINE];
    __shared__ float swred[4][12];
    __shared__ float s8[8];
    __shared__ int amLast;
    const int tid = threadIdx.x, bid = blockIdx.x;
    int batch = bid >> 5;
    const int* gh = (const int*)wsf + WS_HIST + batch * K_FINE;
    for (int i = tid; i < K_FINE; i += NTHR) lh[i] = gh[i];
    __syncthreads();
    int binLocal = tid >> 5, slice = tid & 31;
    int bin = (bid & 31) * 8 + binLocal;
    const float delta = 1.0f / 256.0f;
    const float r   = expf(3.0f * delta);
    const float rm1 = r - 1.0f;
    const float c32 = expf(-3.0f * 32.0f / (float)K_FINE);
    float L = (float)bin * delta;
    float u = expf(3.0f * (L - ((float)slice + 0.5f) * (1.0f / (float)K_FINE)));
    float h = 0.f;
    #pragma unroll 4
    for (int j = slice; j < K_FINE; j += 32) {
        float cnt = (float)lh[j];
        float t1 = 1.0f + u;
        float t2 = fmaf(u, r, 1.0f);
        h = fmaf(cnt * (u * rm1), __builtin_amdgcn_rcpf(t1 * t2), h);
        u *= c32;
    }
    #pragma unroll
    for (int off = 16; off; off >>= 1) h += __shfl_down(h, off, 32);
    if (slice == 0) s8[binLocal] = h;
    __syncthreads();
    if (tid == 0) {
        float hl = 0.f;
        #pragma unroll
        for (int b = 0; b < 8; b++) {
            float hh = s8[b];
            hl += (hh > 0.f) ? hh * logf(hh) : 0.f;
        }
        wsf[WS_UNIF + bid] = hl;
        __threadfence();
        int old = atomicAdd((int*)wsf + WS_CTR, 1);
        amLast = (old == NSOFT - 1);
    }
    __syncthreads();
    if (!amLast) return;

    // ---- final combine (last softhist finisher) ----
    __threadfence();  // acquire: all UNIF partials visible
    float xmn, xinv, tmn, tinv, dmn, dinv;
    reduce_minmax(wsf, swred, tid, xmn, xinv, tmn, tinv, dmn, dinv);
    (void)tmn; (void)tinv;
    float sxd  = wsf[WS_SUM + tid];
    float sx   = wsf[WS_SUM + 256 + tid];
    float sd   = wsf[WS_SUM + 512 + tid];
    float bsum = 0.f;
    for (int i = tid; i < NTILE; i += NTHR) bsum += wsf[WS_SSIM + i];
    float c = wsf[WS_UNIF + tid];
    float* r0 = (float*)lh;          // 5*256 floats fit in lh (2048 words)
    float* r1 = r0 + 256; float* r2 = r1 + 256;
    float* r3 = r2 + 256; float* r4 = r3 + 256;
    r0[tid] = sxd; r1[tid] = sx; r2[tid] = sd; r3[tid] = bsum; r4[tid] = c;
    __syncthreads();
    for (int s = 128; s; s >>= 1) {
        if (tid < s) {
            r0[tid] += r0[tid + s]; r1[tid] += r1[tid + s];
            r2[tid] += r2[tid + s]; r3[tid] += r3[tid + s];
            r4[tid] += r4[tid + s];
        }
        __syncthreads();
    }
    if (tid == 0) {
        float SXD = r0[0], SX = r1[0], SD = r2[0];
        float uniform  = r4[0] / 8.0f;
        float depthNum = SXD - xmn * SD - dmn * SX + (float)N1 * xmn * dmn;
        float depthL   = xinv * dinv * depthNum / 8.0f;
        float ssimMean = r3[0] / (float)N1;
        out[0] = 1e-6f * uniform + 1e-5f * depthL + (1.0f - ssimMean);
    }
}

extern "C" void kernel_launch(void* const* d_in, const int* in_sizes, int n_in,
                              void* d_out, int out_size, void* d_ws, size_t ws_size,
                              hipStream_t stream) {
    const float* x  = (const float*)d_in[0];
    const float* tg = (const float*)d_in[1];
    const float* dp = (const float*)d_in[2];
    float* wsf = (float*)d_ws;
    float* out = (float*)d_out;
    hipLaunchKernelGGL(k_minmax,     dim3(256),   dim3(NTHR), 0, stream, x, tg, dp, wsf);
    hipLaunchKernelGGL(k_work,       dim3(TOTAL), dim3(NTHR), 0, stream, x, tg, wsf);
    hipLaunchKernelGGL(k_soft_final, dim3(NSOFT), dim3(NTHR), 0, stream, wsf, out);
}